// Round 16
// baseline (174.949 us; speedup 1.0000x reference)
//
#include <hip/hip_runtime.h>
#include <cstddef>
#include <cstdint>

#define FN_ 100000
#define V_  50000
#define B_  8
// 100000 = 3125 * 32 -> each wave owns exactly 32 columns (128B store lines).
#define WPB   8                     // waves per block (512 threads)
#define NBLK  3125                  // 25000 wave-tiles / 8

// d_ws layout (bytes):
//   0     : L1 K16 weights, 16 tiles x 512B (16 rows x 16 k, frag-ordered) -> LDS
//           rows 0-63 c1, 64-127 e0, 128-191 e1, 192-255 e2; k semantics:
//           0-8 = corner verts, 9-11 = center, 12 = folded BN shift (X[12]=1)
//   8192  : c2, 8 tiles x 1KB (K32 frag order)   -> per-use global (br0 only; s-pattern)
//   16384 : v2, 8 tiles x 1KB (x1/3 folded)      -> LDS (read 3x per tile)
//   24576 : s,  16 tiles x 1KB                   -> per-use global (L2-hot; R10-validated)
//   40960 : shs f32[448] (256 c2, 320 v2, 384 s)
#define WS_SHS_OFF 40960

typedef _Float16 f16;
typedef f16   f16x4 __attribute__((ext_vector_type(4)));
typedef f16   f16x8 __attribute__((ext_vector_type(8)));
typedef float f32x4 __attribute__((ext_vector_type(4)));

struct Ptrs { const void* p[33]; };

union Pk4h { f16 h[4]; uint2 u; };
union Pk8 { f16 h[8]; uint4 u; };
union FragU4 { uint32_t u[2]; f16x4 v; };

__device__ __forceinline__ uint32_t pack2(float a, float b) {
  return __builtin_bit_cast(uint32_t, __builtin_amdgcn_cvt_pkrtz(a, b));
}
__device__ __forceinline__ uint32_t pack_relu2(float a, float b) {
  uint32_t r, x = pack2(a, b);
  asm("v_pk_max_f16 %0, %1, 0" : "=v"(r) : "v"(x));
  return r;
}

// ---------------- prep: fold BN into f16 weights, fragment-ordered ----------------
// (K32 loop bound 2048 — the R13/R14 2560 bound overwrote shsG; fixed in R15.)
__global__ __launch_bounds__(1024) void sd_prep(Ptrs in, f16* __restrict__ wsW,
                                                float* __restrict__ shsG)
{
  const float* __restrict__ cw1 = (const float*)in.p[3];
  const float* __restrict__ cb1 = (const float*)in.p[4];
  const float* __restrict__ c1g = (const float*)in.p[5];
  const float* __restrict__ c1bt= (const float*)in.p[6];
  const float* __restrict__ c1m = (const float*)in.p[7];
  const float* __restrict__ c1v = (const float*)in.p[8];
  const float* __restrict__ cw2 = (const float*)in.p[9];
  const float* __restrict__ cb2 = (const float*)in.p[10];
  const float* __restrict__ c2g = (const float*)in.p[11];
  const float* __restrict__ c2bt= (const float*)in.p[12];
  const float* __restrict__ c2m = (const float*)in.p[13];
  const float* __restrict__ c2v = (const float*)in.p[14];
  const float* __restrict__ vw1 = (const float*)in.p[15];
  const float* __restrict__ vb1 = (const float*)in.p[16];
  const float* __restrict__ v1g = (const float*)in.p[17];
  const float* __restrict__ v1bt= (const float*)in.p[18];
  const float* __restrict__ v1m = (const float*)in.p[19];
  const float* __restrict__ v1v = (const float*)in.p[20];
  const float* __restrict__ vw2 = (const float*)in.p[21];
  const float* __restrict__ vb2 = (const float*)in.p[22];
  const float* __restrict__ v2g = (const float*)in.p[23];
  const float* __restrict__ v2bt= (const float*)in.p[24];
  const float* __restrict__ v2m = (const float*)in.p[25];
  const float* __restrict__ v2v = (const float*)in.p[26];
  const float* __restrict__ sw  = (const float*)in.p[27];
  const float* __restrict__ sb  = (const float*)in.p[28];
  const float* __restrict__ s1g = (const float*)in.p[29];
  const float* __restrict__ s1bt= (const float*)in.p[30];
  const float* __restrict__ s1m = (const float*)in.p[31];
  const float* __restrict__ s1v = (const float*)in.p[32];

  __shared__ float scsL[448];
  __shared__ float shfL[256];       // L1 shifts for the bias-column trick
  const int tid = threadIdx.x;

  if (tid < 448) {
    const float *g, *v, *bb, *m, *bt; int o; float mul = 1.f;
    if (tid < 64)       { o = tid;      g=c1g; v=c1v; bb=cb1; m=c1m; bt=c1bt; }
    else if (tid < 256) { o = tid & 63; g=v1g; v=v1v; bb=vb1; m=v1m; bt=v1bt; }
    else if (tid < 320) { o = tid-256;  g=c2g; v=c2v; bb=cb2; m=c2m; bt=c2bt; }
    else if (tid < 384) { o = tid-320;  g=v2g; v=v2v; bb=vb2; m=v2m; bt=v2bt; mul = 1.f/3.f; }
    else                { o = tid-384;  g=s1g; v=s1v; bb=sb;  m=s1m; bt=s1bt; }
    float s = g[o] * rsqrtf(v[o] + 1e-5f);
    float sh = ((bb[o] - m[o]) * s + bt[o]) * mul;
    scsL[tid] = s * mul;
    shsG[tid] = sh;
    if (tid < 256) shfL[tid] = sh;
  }
  __syncthreads();

  // ---- L1 K16 region: 16 tiles x 512B, one 8B unit per thread ----
  {
    const int t = tid >> 6, l = tid & 63, r15l = l & 15, g4l = l >> 4;
    const int row = 16*t + r15l;
    const int wm = t >> 2;
    Pk4h pk;
#pragma unroll
    for (int j = 0; j < 4; ++j) {
      const int k = 4*g4l + j; float val = 0.f;
      if (wm == 0) { if (k >= 9 && k < 12) val = cw1[row*3 + (k-9)]; }
      else if (k < 9) {
        const int e = wm - 1, o = row - 64*wm, c = (k - 3*e + 9) % 9;
        if (c < 6) val = vw1[o*6 + c];
      }
      pk.h[j] = (k == 12) ? (f16)shfL[row] : (f16)(val * scsL[row]);
    }
    *(uint2*)((char*)wsW + t*512 + l*8) = pk.u;
  }

  // ---- K32 region: 32 tiles (c2 0-7, v2 8-15, s 16-31) at byte 8192 ----
  for (int u = tid; u < 2048; u += 1024) {
    const int t = u >> 6, l = u & 63, r15l = l & 15, g4l = l >> 4;
    Pk8 pk;
    if (t < 8) {                                    // c2
      const int rt = t >> 1, s = t & 1, row = 16*rt + r15l;
#pragma unroll
      for (int j = 0; j < 8; ++j) { const int k = 32*s + 8*g4l + j;
        pk.h[j] = (f16)(cw2[row*64 + k] * scsL[256+row]); }
    } else if (t < 16) {                            // v2 (x 1/3)
      const int tt = t-8, rt = tt >> 1, s = tt & 1, row = 16*rt + r15l;
#pragma unroll
      for (int j = 0; j < 8; ++j) { const int k = 32*s + 8*g4l + j;
        pk.h[j] = (f16)(vw2[row*64 + k] * scsL[320+row]); }
    } else {                                        // s (64x128)
      const int tt = t-16, rt = tt >> 2, s4 = tt & 3, row = 16*rt + r15l;
#pragma unroll
      for (int j = 0; j < 8; ++j) { const int k = 32*s4 + 8*g4l + j;
        pk.h[j] = (f16)(sw[row*128 + k] * scsL[384+row]); }
    }
    *(uint4*)((char*)wsW + 8192 + t*1024 + l*16) = pk.u;
  }
}

// ---------------- main: wave-autonomous, ONE barrier, 3 blocks/CU ----------------
// Weights-in-LDS law (R13-R15 lesson): L1-K16 + v2 in LDS (16 KB); c2 per-use
// global in br0 only and s per-use global at the tail (both match R10's
// validated s-pattern). LDS 49.7 KB -> 3 blocks/CU -> 6 waves/SIMD.
__global__ __launch_bounds__(512, 6) void sd_main(const int* __restrict__ faces,
    const float* __restrict__ verts, const float* __restrict__ centers,
    const f16* __restrict__ wsW, const float* __restrict__ shsG,
    float* __restrict__ out)
{
  __shared__ f16  Wl[8192];            // 16 KB: L1-K16 (f16 0..4095) + v2 (4096..8191)
  __shared__ f16  Ab[WPB][32 * 64];    // 32 KB: per-wave act buffer, stride 64, swizzled
  __shared__ float shsL[192];          // c2 | v2 | s shifts

  const int tid  = threadIdx.x;
  const int lane = tid & 63;
  const int r15  = lane & 15;
  const int g4   = lane >> 4;
  const int w    = __builtin_amdgcn_readfirstlane(tid >> 6);
  const int sw   = (r15 & 7) << 3;

  // ---- stage L1-K16 + v2 to LDS (16 KB = 1024 uint4; 2 per thread) ----
  {
    const uint4* srcL1 = (const uint4*)wsW;                          // 8 KB
    const uint4* srcV2 = (const uint4*)((const char*)wsW + 16384);   // 8 KB
    uint4* dst = (uint4*)Wl;
    dst[tid]       = srcL1[tid];
    dst[512 + tid] = srcV2[tid];
  }
  if (tid < 192) shsL[tid] = shsG[256 + tid];

  // wave-tile: wt in [0,25000); by = wt/3125, f0 = (wt%3125)*32
  const int wt = blockIdx.x * WPB + w;
  const int by = wt / 3125;
  const int f0 = (wt - by * 3125) * 32;

  // ---- gather X (K16 layout: lane holds k = 4*g4 + j) — validated R13-R15 ----
  FragU4 xf[2];
#pragma unroll
  for (int c = 0; c < 2; ++c) {
    float vals[4] = {0.f, 0.f, 0.f, 0.f};
    const int f = f0 + 16*c + r15;
    const size_t fb3 = ((size_t)by*FN_ + f)*3;
    if (g4 == 0) {            // k0-3: v0.x v0.y v0.z v1.x
      const int i0 = faces[fb3], i1 = faces[fb3+1];
      const float* q0 = verts + ((size_t)by*V_ + (size_t)i0)*3;
      const float* q1 = verts + ((size_t)by*V_ + (size_t)i1)*3;
      vals[0]=q0[0]; vals[1]=q0[1]; vals[2]=q0[2]; vals[3]=q1[0];
    } else if (g4 == 1) {     // k4-7: v1.y v1.z v2.x v2.y
      const int i1 = faces[fb3+1], i2 = faces[fb3+2];
      const float* q1 = verts + ((size_t)by*V_ + (size_t)i1)*3;
      const float* q2 = verts + ((size_t)by*V_ + (size_t)i2)*3;
      vals[0]=q1[1]; vals[1]=q1[2]; vals[2]=q2[0]; vals[3]=q2[1];
    } else if (g4 == 2) {     // k8-11: v2.z c.x c.y c.z
      const int i2 = faces[fb3+2];
      const float* q2 = verts + ((size_t)by*V_ + (size_t)i2)*3;
      vals[0]=q2[2];
      vals[1]=centers[((size_t)by*3+0)*FN_ + f];
      vals[2]=centers[((size_t)by*3+1)*FN_ + f];
      vals[3]=centers[((size_t)by*3+2)*FN_ + f];
    } else {                  // k12-15: bias 1, zeros
      vals[0]=1.0f;
    }
    xf[c].u[0] = pack2(vals[0], vals[1]);
    xf[c].u[1] = pack2(vals[2], vals[3]);
  }
  __syncthreads();

  f16* ab = &Ab[w][0];

  float    vf[4][2][4];
  uint32_t cfp[4][2][2];

  // ================== branch quarters: br0=c1/c2, br1..3=edge/v2 ==================
#pragma unroll
  for (int br = 0; br < 4; ++br) {
    // ---- L1 quarter: K16 MFMAs, A-frags from LDS (b64) ----
    f32x4 acc1[4][2];
#pragma unroll
    for (int t4 = 0; t4 < 4; ++t4) {
      const f16x4 a = *(const f16x4*)&Wl[(4*br + t4)*256 + lane*4];
#pragma unroll
      for (int c = 0; c < 2; ++c) {
        f32x4 z = {0.f,0.f,0.f,0.f};
        acc1[t4][c] = __builtin_amdgcn_mfma_f32_16x16x16f16(a, xf[c].v, z, 0,0,0);
      }
    }
#pragma unroll
    for (int t4 = 0; t4 < 4; ++t4)
#pragma unroll
      for (int c = 0; c < 2; ++c) {
        uint2 pw;
        pw.x = pack_relu2(acc1[t4][c][0], acc1[t4][c][1]);
        pw.y = pack_relu2(acc1[t4][c][2], acc1[t4][c][3]);
        *(uint2*)&ab[(16*c + r15)*64 + ((16*t4 + 4*g4) ^ sw)] = pw;
      }

    // ---- L2 quarter (intra-wave DS order, no barrier) ----
    f16x8 b2[2][2];
#pragma unroll
    for (int c = 0; c < 2; ++c)
#pragma unroll
      for (int s = 0; s < 2; ++s)
        b2[c][s] = *(const f16x8*)&ab[(16*c + r15)*64 + ((32*s + 8*g4) ^ sw)];

    const int shb = br ? 64 : 0;
#pragma unroll
    for (int rt = 0; rt < 4; ++rt) {
      // br0: c2 per-use global (8 loads total, s-pattern); br>=1: v2 from LDS
      const f16x8 a0 = br ? *(const f16x8*)&Wl[4096 + (2*rt    )*512 + lane*8]
                          : *(const f16x8*)((const char*)wsW + 8192 + (2*rt    )*1024 + lane*16);
      const f16x8 a1 = br ? *(const f16x8*)&Wl[4096 + (2*rt + 1)*512 + lane*8]
                          : *(const f16x8*)((const char*)wsW + 8192 + (2*rt + 1)*1024 + lane*16);
      const f32x4 shv = *(const f32x4*)&shsL[shb + rt*16 + 4*g4];
#pragma unroll
      for (int c = 0; c < 2; ++c) {
        f32x4 acc = __builtin_amdgcn_mfma_f32_16x16x32_f16(a0, b2[c][0], shv, 0,0,0);
        acc = __builtin_amdgcn_mfma_f32_16x16x32_f16(a1, b2[c][1], acc, 0,0,0);
        if (br == 0) {
          cfp[rt][c][0] = pack_relu2(acc[0], acc[1]);
          cfp[rt][c][1] = pack_relu2(acc[2], acc[3]);
        } else if (br == 1) {
#pragma unroll
          for (int j = 0; j < 4; ++j) vf[rt][c][j] = fmaxf(acc[j], 0.f);
        } else {
#pragma unroll
          for (int j = 0; j < 4; ++j) vf[rt][c][j] += fmaxf(acc[j], 0.f);
        }
      }
    }
  }

  // ================== L3 in two K-half passes over the same 64-k buffer ==================
  f32x4 acc3[4][2];
#pragma unroll
  for (int rt = 0; rt < 4; ++rt) {
    const f32x4 shv = *(const f32x4*)&shsL[128 + rt*16 + 4*g4];
    acc3[rt][0] = shv; acc3[rt][1] = shv;
  }

#pragma unroll
  for (int half = 0; half < 2; ++half) {
    // write this half's cv (cf for half0, vf for half1)
#pragma unroll
    for (int rt = 0; rt < 4; ++rt)
#pragma unroll
      for (int c = 0; c < 2; ++c) {
        uint2 pw;
        if (half == 0) { pw.x = cfp[rt][c][0]; pw.y = cfp[rt][c][1]; }
        else { pw.x = pack2(vf[rt][c][0], vf[rt][c][1]);
               pw.y = pack2(vf[rt][c][2], vf[rt][c][3]); }
        *(uint2*)&ab[(16*c + r15)*64 + ((16*rt + 4*g4) ^ sw)] = pw;
      }
    // consume: K-steps sg = 2*half + {0,1}; s-weights per-use global (L2-hot)
#pragma unroll
    for (int s = 0; s < 2; ++s) {
      f16x8 b[2];
#pragma unroll
      for (int c = 0; c < 2; ++c)
        b[c] = *(const f16x8*)&ab[(16*c + r15)*64 + ((32*s + 8*g4) ^ sw)];
#pragma unroll
      for (int rt = 0; rt < 4; ++rt) {
        const f16x8 aS = *(const f16x8*)((const char*)wsW + 24576
                                         + (4*rt + 2*half + s)*1024 + lane*16);
        acc3[rt][0] = __builtin_amdgcn_mfma_f32_16x16x32_f16(aS, b[0], acc3[rt][0], 0,0,0);
        acc3[rt][1] = __builtin_amdgcn_mfma_f32_16x16x32_f16(aS, b[1], acc3[rt][1], 0,0,0);
      }
    }
  }

  // ---- stores (32 consecutive cols per wave per row -> full 128B lines) ----
#pragma unroll
  for (int rt = 0; rt < 4; ++rt)
#pragma unroll
    for (int c = 0; c < 2; ++c) {
      const size_t base = ((size_t)(by*64 + rt*16 + 4*g4))*FN_ + (size_t)(f0 + 16*c + r15);
#pragma unroll
      for (int j = 0; j < 4; ++j)
        out[base + (size_t)j*FN_] = fmaxf(acc3[rt][c][j], 0.f);
    }
}

extern "C" void kernel_launch(void* const* d_in, const int* in_sizes, int n_in,
                              void* d_out, int out_size, void* d_ws, size_t ws_size,
                              hipStream_t stream) {
  (void)in_sizes; (void)n_in; (void)out_size; (void)ws_size;
  Ptrs p;
  for (int i = 0; i < 33; ++i) p.p[i] = d_in[i];
  f16*   wsW  = (f16*)d_ws;
  float* shsG = (float*)((char*)d_ws + WS_SHS_OFF);
  hipLaunchKernelGGL(sd_prep, dim3(1), dim3(1024), 0, stream, p, wsW, shsG);
  hipLaunchKernelGGL(sd_main, dim3(NBLK), dim3(512), 0, stream,
                     (const int*)d_in[2], (const float*)d_in[1], (const float*)d_in[0],
                     wsW, shsG, (float*)d_out);
}

// Round 17
// 172.817 us; speedup vs baseline: 1.0123x; 1.0123x over previous
//
#include <hip/hip_runtime.h>
#include <cstddef>
#include <cstdint>

#define FN_ 100000
#define V_  50000
#define B_  8
// 100000 = 3125 * 32 -> each wave owns exactly 32 columns (128B store lines).
#define WPB   8                     // waves per block (512 threads)
#define NBLK  3125                  // 25000 wave-tiles / 8

// d_ws layout (bytes):
//   0     : L1 K16 weights, 16 tiles x 512B (16 rows x 16 k, frag-ordered) -> LDS
//           rows 0-63 c1, 64-127 e0, 128-191 e1, 192-255 e2; k semantics:
//           0-8 = corner verts, 9-11 = center, 12 = folded BN shift (X[12]=1)
//   8192  : c2, 8 tiles x 1KB (K32 frag order)   -> LDS
//   16384 : v2, 8 tiles x 1KB (x1/3 folded)      -> LDS
//   24576 : s,  16 tiles x 1KB                   -> REGISTERS via R11 sfr prefetch
//   40960 : shs f32[448] (256 c2, 320 v2, 384 s)
#define WS_SHS_OFF 40960

typedef _Float16 f16;
typedef f16   f16x4 __attribute__((ext_vector_type(4)));
typedef f16   f16x8 __attribute__((ext_vector_type(8)));
typedef float f32x4 __attribute__((ext_vector_type(4)));

struct Ptrs { const void* p[33]; };

union Pk4h { f16 h[4]; uint2 u; };
union Pk8 { f16 h[8]; uint4 u; };
union FragU4 { uint32_t u[2]; f16x4 v; };

__device__ __forceinline__ uint32_t pack2(float a, float b) {
  return __builtin_bit_cast(uint32_t, __builtin_amdgcn_cvt_pkrtz(a, b));
}
__device__ __forceinline__ uint32_t pack_relu2(float a, float b) {
  uint32_t r, x = pack2(a, b);
  asm("v_pk_max_f16 %0, %1, 0" : "=v"(r) : "v"(x));
  return r;
}

// ---------------- prep: fold BN into f16 weights, fragment-ordered (R15/R16-validated) ----------------
__global__ __launch_bounds__(1024) void sd_prep(Ptrs in, f16* __restrict__ wsW,
                                                float* __restrict__ shsG)
{
  const float* __restrict__ cw1 = (const float*)in.p[3];
  const float* __restrict__ cb1 = (const float*)in.p[4];
  const float* __restrict__ c1g = (const float*)in.p[5];
  const float* __restrict__ c1bt= (const float*)in.p[6];
  const float* __restrict__ c1m = (const float*)in.p[7];
  const float* __restrict__ c1v = (const float*)in.p[8];
  const float* __restrict__ cw2 = (const float*)in.p[9];
  const float* __restrict__ cb2 = (const float*)in.p[10];
  const float* __restrict__ c2g = (const float*)in.p[11];
  const float* __restrict__ c2bt= (const float*)in.p[12];
  const float* __restrict__ c2m = (const float*)in.p[13];
  const float* __restrict__ c2v = (const float*)in.p[14];
  const float* __restrict__ vw1 = (const float*)in.p[15];
  const float* __restrict__ vb1 = (const float*)in.p[16];
  const float* __restrict__ v1g = (const float*)in.p[17];
  const float* __restrict__ v1bt= (const float*)in.p[18];
  const float* __restrict__ v1m = (const float*)in.p[19];
  const float* __restrict__ v1v = (const float*)in.p[20];
  const float* __restrict__ vw2 = (const float*)in.p[21];
  const float* __restrict__ vb2 = (const float*)in.p[22];
  const float* __restrict__ v2g = (const float*)in.p[23];
  const float* __restrict__ v2bt= (const float*)in.p[24];
  const float* __restrict__ v2m = (const float*)in.p[25];
  const float* __restrict__ v2v = (const float*)in.p[26];
  const float* __restrict__ sw  = (const float*)in.p[27];
  const float* __restrict__ sb  = (const float*)in.p[28];
  const float* __restrict__ s1g = (const float*)in.p[29];
  const float* __restrict__ s1bt= (const float*)in.p[30];
  const float* __restrict__ s1m = (const float*)in.p[31];
  const float* __restrict__ s1v = (const float*)in.p[32];

  __shared__ float scsL[448];
  __shared__ float shfL[256];       // L1 shifts for the bias-column trick
  const int tid = threadIdx.x;

  if (tid < 448) {
    const float *g, *v, *bb, *m, *bt; int o; float mul = 1.f;
    if (tid < 64)       { o = tid;      g=c1g; v=c1v; bb=cb1; m=c1m; bt=c1bt; }
    else if (tid < 256) { o = tid & 63; g=v1g; v=v1v; bb=vb1; m=v1m; bt=v1bt; }
    else if (tid < 320) { o = tid-256;  g=c2g; v=c2v; bb=cb2; m=c2m; bt=c2bt; }
    else if (tid < 384) { o = tid-320;  g=v2g; v=v2v; bb=vb2; m=v2m; bt=v2bt; mul = 1.f/3.f; }
    else                { o = tid-384;  g=s1g; v=s1v; bb=sb;  m=s1m; bt=s1bt; }
    float s = g[o] * rsqrtf(v[o] + 1e-5f);
    float sh = ((bb[o] - m[o]) * s + bt[o]) * mul;
    scsL[tid] = s * mul;
    shsG[tid] = sh;
    if (tid < 256) shfL[tid] = sh;
  }
  __syncthreads();

  // ---- L1 K16 region: 16 tiles x 512B, one 8B unit per thread ----
  {
    const int t = tid >> 6, l = tid & 63, r15l = l & 15, g4l = l >> 4;
    const int row = 16*t + r15l;
    const int wm = t >> 2;
    Pk4h pk;
#pragma unroll
    for (int j = 0; j < 4; ++j) {
      const int k = 4*g4l + j; float val = 0.f;
      if (wm == 0) { if (k >= 9 && k < 12) val = cw1[row*3 + (k-9)]; }
      else if (k < 9) {
        const int e = wm - 1, o = row - 64*wm, c = (k - 3*e + 9) % 9;
        if (c < 6) val = vw1[o*6 + c];
      }
      pk.h[j] = (k == 12) ? (f16)shfL[row] : (f16)(val * scsL[row]);
    }
    *(uint2*)((char*)wsW + t*512 + l*8) = pk.u;
  }

  // ---- K32 region: 32 tiles (c2 0-7, v2 8-15, s 16-31) at byte 8192 ----
  for (int u = tid; u < 2048; u += 1024) {
    const int t = u >> 6, l = u & 63, r15l = l & 15, g4l = l >> 4;
    Pk8 pk;
    if (t < 8) {                                    // c2
      const int rt = t >> 1, s = t & 1, row = 16*rt + r15l;
#pragma unroll
      for (int j = 0; j < 8; ++j) { const int k = 32*s + 8*g4l + j;
        pk.h[j] = (f16)(cw2[row*64 + k] * scsL[256+row]); }
    } else if (t < 16) {                            // v2 (x 1/3)
      const int tt = t-8, rt = tt >> 1, s = tt & 1, row = 16*rt + r15l;
#pragma unroll
      for (int j = 0; j < 8; ++j) { const int k = 32*s + 8*g4l + j;
        pk.h[j] = (f16)(vw2[row*64 + k] * scsL[320+row]); }
    } else {                                        // s (64x128)
      const int tt = t-16, rt = tt >> 2, s4 = tt & 3, row = 16*rt + r15l;
#pragma unroll
      for (int j = 0; j < 8; ++j) { const int k = 32*s4 + 8*g4l + j;
        pk.h[j] = (f16)(sw[row*128 + k] * scsL[384+row]); }
    }
    *(uint4*)((char*)wsW + 8192 + t*1024 + l*16) = pk.u;
  }
}

// ---------------- main: R11 structure + L1-K16-from-LDS ----------------
// Laws from R12-R16: weights in LDS except tail s-prefetch (R11-validated);
// launch_bounds min-waves = 4 (6 forces spill); >=32 cols/wave (full lines);
// no persistent weight regs except sfr.
__global__ __launch_bounds__(512, 4) void sd_main(const int* __restrict__ faces,
    const float* __restrict__ verts, const float* __restrict__ centers,
    const f16* __restrict__ wsW, const float* __restrict__ shsG,
    float* __restrict__ out)
{
  __shared__ f16  Wl[12288];           // 24 KB: L1-K16 [0,4096) | c2 [4096,8192) | v2 [8192,12288)
  __shared__ f16  Ab[WPB][32 * 64];    // 32 KB: per-wave act buffer, stride 64, swizzled
  __shared__ float shsL[192];          // c2 | v2 | s shifts

  const int tid  = threadIdx.x;
  const int lane = tid & 63;
  const int r15  = lane & 15;
  const int g4   = lane >> 4;
  const int w    = __builtin_amdgcn_readfirstlane(tid >> 6);
  const int sw   = (r15 & 7) << 3;

  // ---- stage L1-K16 + c2 + v2 to LDS (24 KB contiguous = 1536 uint4) ----
  {
    const uint4* src = (const uint4*)wsW;
    uint4* dst = (uint4*)Wl;
    dst[tid]        = src[tid];
    dst[tid + 512]  = src[tid + 512];
    dst[tid + 1024] = src[tid + 1024];
  }
  if (tid < 192) shsL[tid] = shsG[256 + tid];

  // wave-tile: wt in [0,25000); by = wt/3125, f0 = (wt%3125)*32
  const int wt = blockIdx.x * WPB + w;
  const int by = wt / 3125;
  const int f0 = (wt - by * 3125) * 32;

  // ---- gather X (K16 layout: lane holds k = 4*g4 + j) — validated R13-R16 ----
  FragU4 xf[2];
#pragma unroll
  for (int c = 0; c < 2; ++c) {
    float vals[4] = {0.f, 0.f, 0.f, 0.f};
    const int f = f0 + 16*c + r15;
    const size_t fb3 = ((size_t)by*FN_ + f)*3;
    if (g4 == 0) {            // k0-3: v0.x v0.y v0.z v1.x
      const int i0 = faces[fb3], i1 = faces[fb3+1];
      const float* q0 = verts + ((size_t)by*V_ + (size_t)i0)*3;
      const float* q1 = verts + ((size_t)by*V_ + (size_t)i1)*3;
      vals[0]=q0[0]; vals[1]=q0[1]; vals[2]=q0[2]; vals[3]=q1[0];
    } else if (g4 == 1) {     // k4-7: v1.y v1.z v2.x v2.y
      const int i1 = faces[fb3+1], i2 = faces[fb3+2];
      const float* q1 = verts + ((size_t)by*V_ + (size_t)i1)*3;
      const float* q2 = verts + ((size_t)by*V_ + (size_t)i2)*3;
      vals[0]=q1[1]; vals[1]=q1[2]; vals[2]=q2[0]; vals[3]=q2[1];
    } else if (g4 == 2) {     // k8-11: v2.z c.x c.y c.z
      const int i2 = faces[fb3+2];
      const float* q2 = verts + ((size_t)by*V_ + (size_t)i2)*3;
      vals[0]=q2[2];
      vals[1]=centers[((size_t)by*3+0)*FN_ + f];
      vals[2]=centers[((size_t)by*3+1)*FN_ + f];
      vals[3]=centers[((size_t)by*3+2)*FN_ + f];
    } else {                  // k12-15: bias 1, zeros
      vals[0]=1.0f;
    }
    xf[c].u[0] = pack2(vals[0], vals[1]);
    xf[c].u[1] = pack2(vals[2], vals[3]);
  }
  __syncthreads();

  // ---- prefetch s-weight fragments into registers (R11-validated; loads
  //      overlap the whole L1/L2 phase instead of stalling L3's chain) ----
  f16x8 sfr[16];
#pragma unroll
  for (int i = 0; i < 16; ++i)
    sfr[i] = *(const f16x8*)((const char*)wsW + 24576 + (size_t)i*1024 + lane*16);

  f16* ab = &Ab[w][0];

  float    vf[4][2][4];
  uint32_t cfp[4][2][2];

  // ================== branch quarters: br0=c1/c2, br1..3=edge/v2 ==================
#pragma unroll
  for (int br = 0; br < 4; ++br) {
    // ---- L1 quarter: K16 MFMAs, A-frags from LDS (b64) ----
    f32x4 acc1[4][2];
#pragma unroll
    for (int t4 = 0; t4 < 4; ++t4) {
      const f16x4 a = *(const f16x4*)&Wl[(4*br + t4)*256 + lane*4];
#pragma unroll
      for (int c = 0; c < 2; ++c) {
        f32x4 z = {0.f,0.f,0.f,0.f};
        acc1[t4][c] = __builtin_amdgcn_mfma_f32_16x16x16f16(a, xf[c].v, z, 0,0,0);
      }
    }
#pragma unroll
    for (int t4 = 0; t4 < 4; ++t4)
#pragma unroll
      for (int c = 0; c < 2; ++c) {
        uint2 pw;
        pw.x = pack_relu2(acc1[t4][c][0], acc1[t4][c][1]);
        pw.y = pack_relu2(acc1[t4][c][2], acc1[t4][c][3]);
        *(uint2*)&ab[(16*c + r15)*64 + ((16*t4 + 4*g4) ^ sw)] = pw;
      }

    // ---- L2 quarter (intra-wave DS order, no barrier) ----
    f16x8 b2[2][2];
#pragma unroll
    for (int c = 0; c < 2; ++c)
#pragma unroll
      for (int s = 0; s < 2; ++s)
        b2[c][s] = *(const f16x8*)&ab[(16*c + r15)*64 + ((32*s + 8*g4) ^ sw)];

    const int wb  = br ? 8192 : 4096;   // f16 offset in Wl: v2 : c2
    const int shb = br ? 64 : 0;
#pragma unroll
    for (int rt = 0; rt < 4; ++rt) {
      const f16x8 a0 = *(const f16x8*)&Wl[wb + (2*rt    )*512 + lane*8];
      const f16x8 a1 = *(const f16x8*)&Wl[wb + (2*rt + 1)*512 + lane*8];
      const f32x4 shv = *(const f32x4*)&shsL[shb + rt*16 + 4*g4];
#pragma unroll
      for (int c = 0; c < 2; ++c) {
        f32x4 acc = __builtin_amdgcn_mfma_f32_16x16x32_f16(a0, b2[c][0], shv, 0,0,0);
        acc = __builtin_amdgcn_mfma_f32_16x16x32_f16(a1, b2[c][1], acc, 0,0,0);
        if (br == 0) {
          cfp[rt][c][0] = pack_relu2(acc[0], acc[1]);
          cfp[rt][c][1] = pack_relu2(acc[2], acc[3]);
        } else if (br == 1) {
#pragma unroll
          for (int j = 0; j < 4; ++j) vf[rt][c][j] = fmaxf(acc[j], 0.f);
        } else {
#pragma unroll
          for (int j = 0; j < 4; ++j) vf[rt][c][j] += fmaxf(acc[j], 0.f);
        }
      }
    }
  }

  // ================== L3 in two K-half passes over the same 64-k buffer ==================
  f32x4 acc3[4][2];
#pragma unroll
  for (int rt = 0; rt < 4; ++rt) {
    const f32x4 shv = *(const f32x4*)&shsL[128 + rt*16 + 4*g4];
    acc3[rt][0] = shv; acc3[rt][1] = shv;
  }

#pragma unroll
  for (int half = 0; half < 2; ++half) {
    // write this half's cv (cf for half0, vf for half1)
#pragma unroll
    for (int rt = 0; rt < 4; ++rt)
#pragma unroll
      for (int c = 0; c < 2; ++c) {
        uint2 pw;
        if (half == 0) { pw.x = cfp[rt][c][0]; pw.y = cfp[rt][c][1]; }
        else { pw.x = pack2(vf[rt][c][0], vf[rt][c][1]);
               pw.y = pack2(vf[rt][c][2], vf[rt][c][3]); }
        *(uint2*)&ab[(16*c + r15)*64 + ((16*rt + 4*g4) ^ sw)] = pw;
      }
    // consume: K-steps sg = 2*half + {0,1}
#pragma unroll
    for (int s = 0; s < 2; ++s) {
      f16x8 b[2];
#pragma unroll
      for (int c = 0; c < 2; ++c)
        b[c] = *(const f16x8*)&ab[(16*c + r15)*64 + ((32*s + 8*g4) ^ sw)];
#pragma unroll
      for (int rt = 0; rt < 4; ++rt) {
        const f16x8 aS = sfr[4*rt + 2*half + s];
        acc3[rt][0] = __builtin_amdgcn_mfma_f32_16x16x32_f16(aS, b[0], acc3[rt][0], 0,0,0);
        acc3[rt][1] = __builtin_amdgcn_mfma_f32_16x16x32_f16(aS, b[1], acc3[rt][1], 0,0,0);
      }
    }
  }

  // ---- stores (32 consecutive cols per wave per row -> full 128B lines) ----
#pragma unroll
  for (int rt = 0; rt < 4; ++rt)
#pragma unroll
    for (int c = 0; c < 2; ++c) {
      const size_t base = ((size_t)(by*64 + rt*16 + 4*g4))*FN_ + (size_t)(f0 + 16*c + r15);
#pragma unroll
      for (int j = 0; j < 4; ++j)
        out[base + (size_t)j*FN_] = fmaxf(acc3[rt][c][j], 0.f);
    }
}

extern "C" void kernel_launch(void* const* d_in, const int* in_sizes, int n_in,
                              void* d_out, int out_size, void* d_ws, size_t ws_size,
                              hipStream_t stream) {
  (void)in_sizes; (void)n_in; (void)out_size; (void)ws_size;
  Ptrs p;
  for (int i = 0; i < 33; ++i) p.p[i] = d_in[i];
  f16*   wsW  = (f16*)d_ws;
  float* shsG = (float*)((char*)d_ws + WS_SHS_OFF);
  hipLaunchKernelGGL(sd_prep, dim3(1), dim3(1024), 0, stream, p, wsW, shsG);
  hipLaunchKernelGGL(sd_main, dim3(NBLK), dim3(512), 0, stream,
                     (const int*)d_in[2], (const float*)d_in[1], (const float*)d_in[0],
                     wsW, shsG, (float*)d_out);
}

// Round 18
// 169.247 us; speedup vs baseline: 1.0337x; 1.0211x over previous
//
#include <hip/hip_runtime.h>
#include <cstddef>
#include <cstdint>

#define FN_ 100000
#define V_  50000
#define B_  8
// 100000 = 3125 * 32 -> each wave owns exactly 32 columns, no partial tiles.
#define WPB   8                     // waves per block (512 threads)
#define NBLK  3125                  // 25000 wave-tiles / 8

// d_ws layout (bytes): 48 weight tiles of 1 KB (fragment order), then shs f32[448]
//   tiles  0..15 : combined L1 (256x32): rows 0-63 c1, 64-127 e0, 128-191 e1, 192-255 e2
//                  k==12 column holds the folded BN SHIFT (bias-as-weight; X[12]=1)
//   tiles 16..23 : c2 (64x64)
//   tiles 24..31 : v2 (64x64, x1/3 folded)
//   tiles 32..47 : s  (64x128)   (prefetched to REGISTERS per wave — R11-validated)
#define WS_SHS 49152

typedef _Float16 f16;
typedef f16   f16x8 __attribute__((ext_vector_type(8)));
typedef float f32x4 __attribute__((ext_vector_type(4)));

struct Ptrs { const void* p[33]; };

union Pk8 { f16 h[8]; uint4 u; };
union FragU { uint32_t u[4]; f16x8 v; };

__device__ __forceinline__ uint32_t pack2(float a, float b) {
  return __builtin_bit_cast(uint32_t, __builtin_amdgcn_cvt_pkrtz(a, b));
}
__device__ __forceinline__ uint32_t pack_relu2(float a, float b) {
  uint32_t r, x = pack2(a, b);
  asm("v_pk_max_f16 %0, %1, 0" : "=v"(r) : "v"(x));
  return r;
}

// ---------------- prep: fold BN into f16 weights, fragment-ordered (R10/R11-validated) ----------------
__global__ __launch_bounds__(1024) void sd_prep(Ptrs in, f16* __restrict__ wsW,
                                                float* __restrict__ shsG)
{
  const float* __restrict__ cw1 = (const float*)in.p[3];
  const float* __restrict__ cb1 = (const float*)in.p[4];
  const float* __restrict__ c1g = (const float*)in.p[5];
  const float* __restrict__ c1bt= (const float*)in.p[6];
  const float* __restrict__ c1m = (const float*)in.p[7];
  const float* __restrict__ c1v = (const float*)in.p[8];
  const float* __restrict__ cw2 = (const float*)in.p[9];
  const float* __restrict__ cb2 = (const float*)in.p[10];
  const float* __restrict__ c2g = (const float*)in.p[11];
  const float* __restrict__ c2bt= (const float*)in.p[12];
  const float* __restrict__ c2m = (const float*)in.p[13];
  const float* __restrict__ c2v = (const float*)in.p[14];
  const float* __restrict__ vw1 = (const float*)in.p[15];
  const float* __restrict__ vb1 = (const float*)in.p[16];
  const float* __restrict__ v1g = (const float*)in.p[17];
  const float* __restrict__ v1bt= (const float*)in.p[18];
  const float* __restrict__ v1m = (const float*)in.p[19];
  const float* __restrict__ v1v = (const float*)in.p[20];
  const float* __restrict__ vw2 = (const float*)in.p[21];
  const float* __restrict__ vb2 = (const float*)in.p[22];
  const float* __restrict__ v2g = (const float*)in.p[23];
  const float* __restrict__ v2bt= (const float*)in.p[24];
  const float* __restrict__ v2m = (const float*)in.p[25];
  const float* __restrict__ v2v = (const float*)in.p[26];
  const float* __restrict__ sw  = (const float*)in.p[27];
  const float* __restrict__ sb  = (const float*)in.p[28];
  const float* __restrict__ s1g = (const float*)in.p[29];
  const float* __restrict__ s1bt= (const float*)in.p[30];
  const float* __restrict__ s1m = (const float*)in.p[31];
  const float* __restrict__ s1v = (const float*)in.p[32];

  __shared__ float scsL[448];
  __shared__ float shfL[256];       // L1 shifts for the bias-column trick
  const int tid = threadIdx.x;

  if (tid < 448) {
    const float *g, *v, *bb, *m, *bt; int o; float mul = 1.f;
    if (tid < 64)       { o = tid;      g=c1g; v=c1v; bb=cb1; m=c1m; bt=c1bt; }
    else if (tid < 256) { o = tid & 63; g=v1g; v=v1v; bb=vb1; m=v1m; bt=v1bt; }
    else if (tid < 320) { o = tid-256;  g=c2g; v=c2v; bb=cb2; m=c2m; bt=c2bt; }
    else if (tid < 384) { o = tid-320;  g=v2g; v=v2v; bb=vb2; m=v2m; bt=v2bt; mul = 1.f/3.f; }
    else                { o = tid-384;  g=s1g; v=s1v; bb=sb;  m=s1m; bt=s1bt; }
    float s = g[o] * rsqrtf(v[o] + 1e-5f);
    float sh = ((bb[o] - m[o]) * s + bt[o]) * mul;
    scsL[tid] = s * mul;
    shsG[tid] = sh;
    if (tid < 256) shfL[tid] = sh;
  }
  __syncthreads();

  for (int u = tid; u < 3072; u += 1024) {
    const int t = u >> 6, l = u & 63, r15 = l & 15, g4 = l >> 4;
    Pk8 pk;
    if (t < 16) {                                   // L1 combined 256x32 (+bias col 12)
      const int wm = t >> 2, tr = t & 3, row = 64*wm + 16*tr + r15;
#pragma unroll
      for (int j = 0; j < 8; ++j) {
        const int k = 8*g4 + j; float val = 0.f;
        if (wm == 0) { if (k >= 9 && k < 12) val = cw1[row*3 + (k-9)]; }
        else if (k < 9) {
          const int e = wm - 1, o = row - 64*wm, c = (k - 3*e + 9) % 9;
          if (c < 6) val = vw1[o*6 + c];
        }
        pk.h[j] = (k == 12) ? (f16)shfL[row] : (f16)(val * scsL[row]);
      }
    } else if (t < 24) {                            // c2
      const int tt = t-16, rt = tt >> 1, s = tt & 1, row = 16*rt + r15;
#pragma unroll
      for (int j = 0; j < 8; ++j) { const int k = 32*s + 8*g4 + j;
        pk.h[j] = (f16)(cw2[row*64 + k] * scsL[256+row]); }
    } else if (t < 32) {                            // v2 (x 1/3)
      const int tt = t-24, rt = tt >> 1, s = tt & 1, row = 16*rt + r15;
#pragma unroll
      for (int j = 0; j < 8; ++j) { const int k = 32*s + 8*g4 + j;
        pk.h[j] = (f16)(vw2[row*64 + k] * scsL[320+row]); }
    } else {                                        // s (64x128)
      const int tt = t-32, rt = tt >> 2, s = tt & 3, row = 16*rt + r15;
#pragma unroll
      for (int j = 0; j < 8; ++j) { const int k = 32*s + 8*g4 + j;
        pk.h[j] = (f16)(sw[row*128 + k] * scsL[384+row]); }
    }
    *(uint4*)(wsW + (size_t)t*512 + l*8) = pk.u;
  }
}

// ---------------- main: exact R11 (86.5 us validated) + s_setprio around MFMA clusters ----------------
// T5 mechanism: wave-autonomous structure -> co-resident waves at different
// phases -> scheduler can favor MFMA-issuing waves (attn-regime, m191).
__global__ __launch_bounds__(512, 4) void sd_main(const int* __restrict__ faces,
    const float* __restrict__ verts, const float* __restrict__ centers,
    const f16* __restrict__ wsW, const float* __restrict__ shsG,
    float* __restrict__ out)
{
  __shared__ f16  Wl[32 * 512];        // 32 KB: L1 + c2 + v2 tiles
  __shared__ f16  Ab[WPB][32 * 64];    // 32 KB: per-wave act buffer, stride 64, swizzled
  __shared__ float shsL[192];          // c2 | v2 | s shifts

  const int tid  = threadIdx.x;
  const int lane = tid & 63;
  const int r15  = lane & 15;
  const int g4   = lane >> 4;
  const int w    = __builtin_amdgcn_readfirstlane(tid >> 6);
  const int sw   = (r15 & 7) << 3;

  // ---- stage weights + shifts (the only barrier) ----
  {
    const uint4* src = (const uint4*)wsW;
    uint4* dst = (uint4*)Wl;
#pragma unroll
    for (int i = 0; i < 4; ++i) dst[tid + i*512] = src[tid + i*512];
  }
  if (tid < 192) shsL[tid] = shsG[256 + tid];

  // wave-tile: wt in [0,25000); by = wt/3125, f0 = (wt%3125)*32
  const int wt = blockIdx.x * WPB + w;
  const int by = wt / 3125;
  const int f0 = (wt - by * 3125) * 32;

  // ---- gather X into B-frag registers (lane-direct, no LDS) ----
  FragU xf[2];
#pragma unroll
  for (int c = 0; c < 2; ++c) {
    float vals[8] = {0.f,0.f,0.f,0.f,0.f,0.f,0.f,0.f};
    const int f = f0 + 16*c + r15;
    if (g4 == 0) {
      const size_t fb3 = ((size_t)by*FN_ + f)*3;
      const int i0 = faces[fb3], i1 = faces[fb3+1], i2 = faces[fb3+2];
      const float* q0 = verts + ((size_t)by*V_ + (size_t)i0)*3;
      const float* q1 = verts + ((size_t)by*V_ + (size_t)i1)*3;
      const float* q2 = verts + ((size_t)by*V_ + (size_t)i2)*3;
      vals[0]=q0[0]; vals[1]=q0[1]; vals[2]=q0[2];
      vals[3]=q1[0]; vals[4]=q1[1]; vals[5]=q1[2];
      vals[6]=q2[0]; vals[7]=q2[1];
    } else if (g4 == 1) {
      const size_t fb3 = ((size_t)by*FN_ + f)*3;
      const int i2 = faces[fb3+2];
      const float* q2 = verts + ((size_t)by*V_ + (size_t)i2)*3;
      vals[0]=q2[2];
      vals[1]=centers[((size_t)by*3+0)*FN_ + f];
      vals[2]=centers[((size_t)by*3+1)*FN_ + f];
      vals[3]=centers[((size_t)by*3+2)*FN_ + f];
      vals[4]=1.0f;                                  // bias channel k=12
    }
#pragma unroll
    for (int m = 0; m < 4; ++m) xf[c].u[m] = pack2(vals[2*m], vals[2*m+1]);
  }
  __syncthreads();

  // ---- prefetch s-weight fragments (L2-hot) into registers (R11-validated) ----
  f16x8 sfr[16];
#pragma unroll
  for (int i = 0; i < 16; ++i)
    sfr[i] = *(const f16x8*)(wsW + (size_t)(32 + i)*512 + lane*8);

  f16* ab = &Ab[w][0];

  float    vf[4][2][4];
  uint32_t cfp[4][2][2];

  // ================== branch quarters: br0=c1/c2, br1..3=edge/v2 ==================
#pragma unroll
  for (int br = 0; br < 4; ++br) {
    // ---- L1 quarter: 4 row-tiles x 2 col-frags ----
    f32x4 acc1[4][2];
    __builtin_amdgcn_s_setprio(1);
#pragma unroll
    for (int t4 = 0; t4 < 4; ++t4) {
      const f16x8 a = *(const f16x8*)&Wl[(4*br + t4)*512 + lane*8];
#pragma unroll
      for (int c = 0; c < 2; ++c) {
        f32x4 z = {0.f,0.f,0.f,0.f};
        acc1[t4][c] = __builtin_amdgcn_mfma_f32_16x16x32_f16(a, xf[c].v, z, 0,0,0);
      }
    }
    __builtin_amdgcn_s_setprio(0);
#pragma unroll
    for (int t4 = 0; t4 < 4; ++t4)
#pragma unroll
      for (int c = 0; c < 2; ++c) {
        uint2 pw;
        pw.x = pack_relu2(acc1[t4][c][0], acc1[t4][c][1]);
        pw.y = pack_relu2(acc1[t4][c][2], acc1[t4][c][3]);
        *(uint2*)&ab[(16*c + r15)*64 + ((16*t4 + 4*g4) ^ sw)] = pw;
      }

    // ---- L2 quarter (this wave's own writes; intra-wave DS order, no barrier) ----
    f16x8 b2[2][2];
#pragma unroll
    for (int c = 0; c < 2; ++c)
#pragma unroll
      for (int s = 0; s < 2; ++s)
        b2[c][s] = *(const f16x8*)&ab[(16*c + r15)*64 + ((32*s + 8*g4) ^ sw)];

    const int wb = br ? 24 : 16;
    const int shb = br ? 64 : 0;
    __builtin_amdgcn_s_setprio(1);
#pragma unroll
    for (int rt = 0; rt < 4; ++rt) {
      const f16x8 a0 = *(const f16x8*)&Wl[(wb + 2*rt    )*512 + lane*8];
      const f16x8 a1 = *(const f16x8*)&Wl[(wb + 2*rt + 1)*512 + lane*8];
      const f32x4 shv = *(const f32x4*)&shsL[shb + rt*16 + 4*g4];
#pragma unroll
      for (int c = 0; c < 2; ++c) {
        f32x4 acc = __builtin_amdgcn_mfma_f32_16x16x32_f16(a0, b2[c][0], shv, 0,0,0);
        acc = __builtin_amdgcn_mfma_f32_16x16x32_f16(a1, b2[c][1], acc, 0,0,0);
        if (br == 0) {
          cfp[rt][c][0] = pack_relu2(acc[0], acc[1]);
          cfp[rt][c][1] = pack_relu2(acc[2], acc[3]);
        } else if (br == 1) {
#pragma unroll
          for (int j = 0; j < 4; ++j) vf[rt][c][j] = fmaxf(acc[j], 0.f);
        } else {
#pragma unroll
          for (int j = 0; j < 4; ++j) vf[rt][c][j] += fmaxf(acc[j], 0.f);
        }
      }
    }
    __builtin_amdgcn_s_setprio(0);
  }

  // ================== L3 in two K-half passes over the same 64-k buffer ==================
  f32x4 acc3[4][2];
#pragma unroll
  for (int rt = 0; rt < 4; ++rt) {
    const f32x4 shv = *(const f32x4*)&shsL[128 + rt*16 + 4*g4];
    acc3[rt][0] = shv; acc3[rt][1] = shv;
  }

#pragma unroll
  for (int half = 0; half < 2; ++half) {
    // write this half's cv (cf for half0, vf for half1)
#pragma unroll
    for (int rt = 0; rt < 4; ++rt)
#pragma unroll
      for (int c = 0; c < 2; ++c) {
        uint2 pw;
        if (half == 0) { pw.x = cfp[rt][c][0]; pw.y = cfp[rt][c][1]; }
        else { pw.x = pack2(vf[rt][c][0], vf[rt][c][1]);
               pw.y = pack2(vf[rt][c][2], vf[rt][c][3]); }
        *(uint2*)&ab[(16*c + r15)*64 + ((16*rt + 4*g4) ^ sw)] = pw;
      }
    // consume: K-steps sg = 2*half + {0,1}
    __builtin_amdgcn_s_setprio(1);
#pragma unroll
    for (int s = 0; s < 2; ++s) {
      f16x8 b[2];
#pragma unroll
      for (int c = 0; c < 2; ++c)
        b[c] = *(const f16x8*)&ab[(16*c + r15)*64 + ((32*s + 8*g4) ^ sw)];
#pragma unroll
      for (int rt = 0; rt < 4; ++rt) {
        const f16x8 aS = sfr[4*rt + 2*half + s];
        acc3[rt][0] = __builtin_amdgcn_mfma_f32_16x16x32_f16(aS, b[0], acc3[rt][0], 0,0,0);
        acc3[rt][1] = __builtin_amdgcn_mfma_f32_16x16x32_f16(aS, b[1], acc3[rt][1], 0,0,0);
      }
    }
    __builtin_amdgcn_s_setprio(0);
  }

  // ---- stores (32 consecutive cols per wave per row -> full 128B lines) ----
#pragma unroll
  for (int rt = 0; rt < 4; ++rt)
#pragma unroll
    for (int c = 0; c < 2; ++c) {
      const size_t base = ((size_t)(by*64 + rt*16 + 4*g4))*FN_ + (size_t)(f0 + 16*c + r15);
#pragma unroll
      for (int j = 0; j < 4; ++j)
        out[base + (size_t)j*FN_] = fmaxf(acc3[rt][c][j], 0.f);
    }
}

extern "C" void kernel_launch(void* const* d_in, const int* in_sizes, int n_in,
                              void* d_out, int out_size, void* d_ws, size_t ws_size,
                              hipStream_t stream) {
  (void)in_sizes; (void)n_in; (void)out_size; (void)ws_size;
  Ptrs p;
  for (int i = 0; i < 33; ++i) p.p[i] = d_in[i];
  f16*   wsW  = (f16*)d_ws;
  float* shsG = (float*)((char*)d_ws + WS_SHS);
  hipLaunchKernelGGL(sd_prep, dim3(1), dim3(1024), 0, stream, p, wsW, shsG);
  hipLaunchKernelGGL(sd_main, dim3(NBLK), dim3(512), 0, stream,
                     (const int*)d_in[2], (const float*)d_in[1], (const float*)d_in[0],
                     wsW, shsG, (float*)d_out);
}

// Round 19
// 91.070 us; speedup vs baseline: 1.9211x; 1.8584x over previous
//
#include <hip/hip_runtime.h>
#include <cstddef>
#include <cstdint>

#define FN_ 100000
#define V_  50000
#define B_  8
// 100000 = 3125 * 32 -> each wave owns exactly 32 columns, no partial tiles.
#define WPB   8                     // waves per block (512 threads)
#define NBLK  3125                  // 25000 wave-tiles / 8

// d_ws layout (bytes): 48 weight tiles of 1 KB (fragment order), then shs f32[448]
//   tiles  0..15 : combined L1 (256x32): rows 0-63 c1, 64-127 e0, 128-191 e1, 192-255 e2
//                  k==12 column holds the folded BN SHIFT (bias-as-weight; X[12]=1)
//   tiles 16..23 : c2 (64x64)
//   tiles 24..31 : v2 (64x64, x1/3 folded)
//   tiles 32..47 : s  (64x128)   (prefetched to REGISTERS per wave)
#define WS_SHS 49152

typedef _Float16 f16;
typedef f16   f16x8 __attribute__((ext_vector_type(8)));
typedef float f32x4 __attribute__((ext_vector_type(4)));

struct Ptrs { const void* p[33]; };

union Pk8 { f16 h[8]; uint4 u; };
union FragU { uint32_t u[4]; f16x8 v; };

__device__ __forceinline__ uint32_t pack2(float a, float b) {
  return __builtin_bit_cast(uint32_t, __builtin_amdgcn_cvt_pkrtz(a, b));
}
__device__ __forceinline__ uint32_t pack_relu2(float a, float b) {
  uint32_t r, x = pack2(a, b);
  asm("v_pk_max_f16 %0, %1, 0" : "=v"(r) : "v"(x));
  return r;
}

// ---------------- prep: fold BN into f16 weights, fragment-ordered ----------------
__global__ __launch_bounds__(1024) void sd_prep(Ptrs in, f16* __restrict__ wsW,
                                                float* __restrict__ shsG)
{
  const float* __restrict__ cw1 = (const float*)in.p[3];
  const float* __restrict__ cb1 = (const float*)in.p[4];
  const float* __restrict__ c1g = (const float*)in.p[5];
  const float* __restrict__ c1bt= (const float*)in.p[6];
  const float* __restrict__ c1m = (const float*)in.p[7];
  const float* __restrict__ c1v = (const float*)in.p[8];
  const float* __restrict__ cw2 = (const float*)in.p[9];
  const float* __restrict__ cb2 = (const float*)in.p[10];
  const float* __restrict__ c2g = (const float*)in.p[11];
  const float* __restrict__ c2bt= (const float*)in.p[12];
  const float* __restrict__ c2m = (const float*)in.p[13];
  const float* __restrict__ c2v = (const float*)in.p[14];
  const float* __restrict__ vw1 = (const float*)in.p[15];
  const float* __restrict__ vb1 = (const float*)in.p[16];
  const float* __restrict__ v1g = (const float*)in.p[17];
  const float* __restrict__ v1bt= (const float*)in.p[18];
  const float* __restrict__ v1m = (const float*)in.p[19];
  const float* __restrict__ v1v = (const float*)in.p[20];
  const float* __restrict__ vw2 = (const float*)in.p[21];
  const float* __restrict__ vb2 = (const float*)in.p[22];
  const float* __restrict__ v2g = (const float*)in.p[23];
  const float* __restrict__ v2bt= (const float*)in.p[24];
  const float* __restrict__ v2m = (const float*)in.p[25];
  const float* __restrict__ v2v = (const float*)in.p[26];
  const float* __restrict__ sw  = (const float*)in.p[27];
  const float* __restrict__ sb  = (const float*)in.p[28];
  const float* __restrict__ s1g = (const float*)in.p[29];
  const float* __restrict__ s1bt= (const float*)in.p[30];
  const float* __restrict__ s1m = (const float*)in.p[31];
  const float* __restrict__ s1v = (const float*)in.p[32];

  __shared__ float scsL[448];
  __shared__ float shfL[256];       // L1 shifts for the bias-column trick
  const int tid = threadIdx.x;

  if (tid < 448) {
    const float *g, *v, *bb, *m, *bt; int o; float mul = 1.f;
    if (tid < 64)       { o = tid;      g=c1g; v=c1v; bb=cb1; m=c1m; bt=c1bt; }
    else if (tid < 256) { o = tid & 63; g=v1g; v=v1v; bb=vb1; m=v1m; bt=v1bt; }
    else if (tid < 320) { o = tid-256;  g=c2g; v=c2v; bb=cb2; m=c2m; bt=c2bt; }
    else if (tid < 384) { o = tid-320;  g=v2g; v=v2v; bb=vb2; m=v2m; bt=v2bt; mul = 1.f/3.f; }
    else                { o = tid-384;  g=s1g; v=s1v; bb=sb;  m=s1m; bt=s1bt; }
    float s = g[o] * rsqrtf(v[o] + 1e-5f);
    float sh = ((bb[o] - m[o]) * s + bt[o]) * mul;
    scsL[tid] = s * mul;
    shsG[tid] = sh;
    if (tid < 256) shfL[tid] = sh;
  }
  __syncthreads();

  for (int u = tid; u < 3072; u += 1024) {
    const int t = u >> 6, l = u & 63, r15 = l & 15, g4 = l >> 4;
    Pk8 pk;
    if (t < 16) {                                   // L1 combined 256x32 (+bias col 12)
      const int wm = t >> 2, tr = t & 3, row = 64*wm + 16*tr + r15;
#pragma unroll
      for (int j = 0; j < 8; ++j) {
        const int k = 8*g4 + j; float val = 0.f;
        if (wm == 0) { if (k >= 9 && k < 12) val = cw1[row*3 + (k-9)]; }
        else if (k < 9) {
          const int e = wm - 1, o = row - 64*wm, c = (k - 3*e + 9) % 9;
          if (c < 6) val = vw1[o*6 + c];
        }
        pk.h[j] = (k == 12) ? (f16)shfL[row] : (f16)(val * scsL[row]);
      }
    } else if (t < 24) {                            // c2
      const int tt = t-16, rt = tt >> 1, s = tt & 1, row = 16*rt + r15;
#pragma unroll
      for (int j = 0; j < 8; ++j) { const int k = 32*s + 8*g4 + j;
        pk.h[j] = (f16)(cw2[row*64 + k] * scsL[256+row]); }
    } else if (t < 32) {                            // v2 (x 1/3)
      const int tt = t-24, rt = tt >> 1, s = tt & 1, row = 16*rt + r15;
#pragma unroll
      for (int j = 0; j < 8; ++j) { const int k = 32*s + 8*g4 + j;
        pk.h[j] = (f16)(vw2[row*64 + k] * scsL[320+row]); }
    } else {                                        // s (64x128)
      const int tt = t-32, rt = tt >> 2, s = tt & 3, row = 16*rt + r15;
#pragma unroll
      for (int j = 0; j < 8; ++j) { const int k = 32*s + 8*g4 + j;
        pk.h[j] = (f16)(sw[row*128 + k] * scsL[384+row]); }
    }
    *(uint4*)(wsW + (size_t)t*512 + l*8) = pk.u;
  }
}

// ---------------- main: wave-autonomous, ONE barrier (exact R11, validated 86.5 us) ----------------
// No setprio (R18: scheduling-fence -> +32 live acc regs -> spill). No K16
// (R13-R17 pathology). No per-use global weights except the sfr tail. No
// launch_bounds min-waves > 4. 32 cols/wave (full 128B store lines).
__global__ __launch_bounds__(512, 4) void sd_main(const int* __restrict__ faces,
    const float* __restrict__ verts, const float* __restrict__ centers,
    const f16* __restrict__ wsW, const float* __restrict__ shsG,
    float* __restrict__ out)
{
  __shared__ f16  Wl[32 * 512];        // 32 KB: L1 + c2 + v2 tiles
  __shared__ f16  Ab[WPB][32 * 64];    // 32 KB: per-wave act buffer, stride 64, swizzled
  __shared__ float shsL[192];          // c2 | v2 | s shifts

  const int tid  = threadIdx.x;
  const int lane = tid & 63;
  const int r15  = lane & 15;
  const int g4   = lane >> 4;
  const int w    = __builtin_amdgcn_readfirstlane(tid >> 6);
  const int sw   = (r15 & 7) << 3;

  // ---- stage weights + shifts (the only barrier) ----
  {
    const uint4* src = (const uint4*)wsW;
    uint4* dst = (uint4*)Wl;
#pragma unroll
    for (int i = 0; i < 4; ++i) dst[tid + i*512] = src[tid + i*512];
  }
  if (tid < 192) shsL[tid] = shsG[256 + tid];

  // wave-tile: wt in [0,25000); by = wt/3125, f0 = (wt%3125)*32
  const int wt = blockIdx.x * WPB + w;
  const int by = wt / 3125;
  const int f0 = (wt - by * 3125) * 32;

  // ---- gather X into B-frag registers (lane-direct, no LDS) ----
  FragU xf[2];
#pragma unroll
  for (int c = 0; c < 2; ++c) {
    float vals[8] = {0.f,0.f,0.f,0.f,0.f,0.f,0.f,0.f};
    const int f = f0 + 16*c + r15;
    if (g4 == 0) {
      const size_t fb3 = ((size_t)by*FN_ + f)*3;
      const int i0 = faces[fb3], i1 = faces[fb3+1], i2 = faces[fb3+2];
      const float* q0 = verts + ((size_t)by*V_ + (size_t)i0)*3;
      const float* q1 = verts + ((size_t)by*V_ + (size_t)i1)*3;
      const float* q2 = verts + ((size_t)by*V_ + (size_t)i2)*3;
      vals[0]=q0[0]; vals[1]=q0[1]; vals[2]=q0[2];
      vals[3]=q1[0]; vals[4]=q1[1]; vals[5]=q1[2];
      vals[6]=q2[0]; vals[7]=q2[1];
    } else if (g4 == 1) {
      const size_t fb3 = ((size_t)by*FN_ + f)*3;
      const int i2 = faces[fb3+2];
      const float* q2 = verts + ((size_t)by*V_ + (size_t)i2)*3;
      vals[0]=q2[2];
      vals[1]=centers[((size_t)by*3+0)*FN_ + f];
      vals[2]=centers[((size_t)by*3+1)*FN_ + f];
      vals[3]=centers[((size_t)by*3+2)*FN_ + f];
      vals[4]=1.0f;                                  // bias channel k=12
    }
#pragma unroll
    for (int m = 0; m < 4; ++m) xf[c].u[m] = pack2(vals[2*m], vals[2*m+1]);
  }
  __syncthreads();

  // ---- prefetch s-weight fragments (L2-hot) into registers; loads overlap
  //      the whole L1/L2 phase instead of stalling L3's chain ----
  f16x8 sfr[16];
#pragma unroll
  for (int i = 0; i < 16; ++i)
    sfr[i] = *(const f16x8*)(wsW + (size_t)(32 + i)*512 + lane*8);

  f16* ab = &Ab[w][0];

  float    vf[4][2][4];
  uint32_t cfp[4][2][2];

  // ================== branch quarters: br0=c1/c2, br1..3=edge/v2 ==================
#pragma unroll
  for (int br = 0; br < 4; ++br) {
    // ---- L1 quarter: 4 row-tiles x 2 col-frags ----
    f32x4 acc1[4][2];
#pragma unroll
    for (int t4 = 0; t4 < 4; ++t4) {
      const f16x8 a = *(const f16x8*)&Wl[(4*br + t4)*512 + lane*8];
#pragma unroll
      for (int c = 0; c < 2; ++c) {
        f32x4 z = {0.f,0.f,0.f,0.f};
        acc1[t4][c] = __builtin_amdgcn_mfma_f32_16x16x32_f16(a, xf[c].v, z, 0,0,0);
      }
    }
#pragma unroll
    for (int t4 = 0; t4 < 4; ++t4)
#pragma unroll
      for (int c = 0; c < 2; ++c) {
        uint2 pw;
        pw.x = pack_relu2(acc1[t4][c][0], acc1[t4][c][1]);
        pw.y = pack_relu2(acc1[t4][c][2], acc1[t4][c][3]);
        *(uint2*)&ab[(16*c + r15)*64 + ((16*t4 + 4*g4) ^ sw)] = pw;
      }

    // ---- L2 quarter (this wave's own writes; intra-wave DS order, no barrier) ----
    f16x8 b2[2][2];
#pragma unroll
    for (int c = 0; c < 2; ++c)
#pragma unroll
      for (int s = 0; s < 2; ++s)
        b2[c][s] = *(const f16x8*)&ab[(16*c + r15)*64 + ((32*s + 8*g4) ^ sw)];

    const int wb = br ? 24 : 16;
    const int shb = br ? 64 : 0;
#pragma unroll
    for (int rt = 0; rt < 4; ++rt) {
      const f16x8 a0 = *(const f16x8*)&Wl[(wb + 2*rt    )*512 + lane*8];
      const f16x8 a1 = *(const f16x8*)&Wl[(wb + 2*rt + 1)*512 + lane*8];
      const f32x4 shv = *(const f32x4*)&shsL[shb + rt*16 + 4*g4];
#pragma unroll
      for (int c = 0; c < 2; ++c) {
        f32x4 acc = __builtin_amdgcn_mfma_f32_16x16x32_f16(a0, b2[c][0], shv, 0,0,0);
        acc = __builtin_amdgcn_mfma_f32_16x16x32_f16(a1, b2[c][1], acc, 0,0,0);
        if (br == 0) {
          cfp[rt][c][0] = pack_relu2(acc[0], acc[1]);
          cfp[rt][c][1] = pack_relu2(acc[2], acc[3]);
        } else if (br == 1) {
#pragma unroll
          for (int j = 0; j < 4; ++j) vf[rt][c][j] = fmaxf(acc[j], 0.f);
        } else {
#pragma unroll
          for (int j = 0; j < 4; ++j) vf[rt][c][j] += fmaxf(acc[j], 0.f);
        }
      }
    }
  }

  // ================== L3 in two K-half passes over the same 64-k buffer ==================
  f32x4 acc3[4][2];
#pragma unroll
  for (int rt = 0; rt < 4; ++rt) {
    const f32x4 shv = *(const f32x4*)&shsL[128 + rt*16 + 4*g4];
    acc3[rt][0] = shv; acc3[rt][1] = shv;
  }

#pragma unroll
  for (int half = 0; half < 2; ++half) {
    // write this half's cv (cf for half0, vf for half1)
#pragma unroll
    for (int rt = 0; rt < 4; ++rt)
#pragma unroll
      for (int c = 0; c < 2; ++c) {
        uint2 pw;
        if (half == 0) { pw.x = cfp[rt][c][0]; pw.y = cfp[rt][c][1]; }
        else { pw.x = pack2(vf[rt][c][0], vf[rt][c][1]);
               pw.y = pack2(vf[rt][c][2], vf[rt][c][3]); }
        *(uint2*)&ab[(16*c + r15)*64 + ((16*rt + 4*g4) ^ sw)] = pw;
      }
    // consume: K-steps sg = 2*half + {0,1}
#pragma unroll
    for (int s = 0; s < 2; ++s) {
      f16x8 b[2];
#pragma unroll
      for (int c = 0; c < 2; ++c)
        b[c] = *(const f16x8*)&ab[(16*c + r15)*64 + ((32*s + 8*g4) ^ sw)];
#pragma unroll
      for (int rt = 0; rt < 4; ++rt) {
        const f16x8 aS = sfr[4*rt + 2*half + s];
        acc3[rt][0] = __builtin_amdgcn_mfma_f32_16x16x32_f16(aS, b[0], acc3[rt][0], 0,0,0);
        acc3[rt][1] = __builtin_amdgcn_mfma_f32_16x16x32_f16(aS, b[1], acc3[rt][1], 0,0,0);
      }
    }
  }

  // ---- stores (32 consecutive cols per wave per row -> full 128B lines) ----
#pragma unroll
  for (int rt = 0; rt < 4; ++rt)
#pragma unroll
    for (int c = 0; c < 2; ++c) {
      const size_t base = ((size_t)(by*64 + rt*16 + 4*g4))*FN_ + (size_t)(f0 + 16*c + r15);
#pragma unroll
      for (int j = 0; j < 4; ++j)
        out[base + (size_t)j*FN_] = fmaxf(acc3[rt][c][j], 0.f);
    }
}

extern "C" void kernel_launch(void* const* d_in, const int* in_sizes, int n_in,
                              void* d_out, int out_size, void* d_ws, size_t ws_size,
                              hipStream_t stream) {
  (void)in_sizes; (void)n_in; (void)out_size; (void)ws_size;
  Ptrs p;
  for (int i = 0; i < 33; ++i) p.p[i] = d_in[i];
  f16*   wsW  = (f16*)d_ws;
  float* shsG = (float*)((char*)d_ws + WS_SHS);
  hipLaunchKernelGGL(sd_prep, dim3(1), dim3(1024), 0, stream, p, wsW, shsG);
  hipLaunchKernelGGL(sd_main, dim3(NBLK), dim3(512), 0, stream,
                     (const int*)d_in[2], (const float*)d_in[1], (const float*)d_in[0],
                     wsW, shsG, (float*)d_out);
}